// Round 7
// baseline (294.470 us; speedup 1.0000x reference)
//
#include <hip/hip_runtime.h>
#include <stdint.h>

// ---------------------------------------------------------------------------
// LocalBranch: ResNetMLP (5x GEMM+LN) + per-graph distance softmax pool.
// R17: IN-REGISTER LN — delete Yb and the phase-A/B LDS transpose.
//     R16 post-mortem: spill persisted (WRITE 66MB) despite streaming phase B;
//     structure itself (Yb round-trip, 4 barriers/layer, par staging) is the
//     cost. New per-layer flow: K-loop -> bias add in acc -> per-lane partial
//     stats -> red16 (wave's 32 cols) -> 8 masked ds_add_f32 atomics into a
//     64-float pt buffer (double-buffered across layers) -> ONE barrier ->
//     all lanes read row totals (broadcast), compute rstd/nmr, normalize acc
//     in regs, relu+residual (xprev stays acc-domain), pack bf16 via quad-perm
//     DPP lane pairs, store next Xb directly. Head stages z through the freed
//     Xb region for coalesced Z stores. Barriers 4->2/layer, LDS 36->17.4KB,
//     par staging -> 6 scalar global loads issued pre-K-loop.
// R15: waves_per_eu(6) -> 3 blocks/CU (kept).
// R14: 512-thr blocks (32 rows, 8 waves, 4096 blocks) (kept).
// ---------------------------------------------------------------------------

typedef __attribute__((ext_vector_type(8))) short bf16x8;   // 8 bf16 = 4 VGPRs
typedef __attribute__((ext_vector_type(4))) float f32x4;

#define XB_STRIDE 264            // bf16 elems; 132 dwords/row
#define ZB_STRIDE 136            // pool Z tile 128+8
#define LDS_PT    16896          // byte offset: pt after Xb (32*264*2); 16B-aligned
#define LDS_TOTAL 17408          // + 2*64 floats

__device__ __forceinline__ unsigned int rne16(float f) {
  unsigned int u = __builtin_bit_cast(unsigned int, f);
  return u + 0x7fffu + ((u >> 16) & 1u);     // RNE bf16 in high 16 bits
}
__device__ __forceinline__ unsigned short f2bf(float f) {
  return (unsigned short)(rne16(f) >> 16);
}
__device__ __forceinline__ float bf2f(unsigned short h) {
  unsigned int u = ((unsigned int)h) << 16;
  return __builtin_bit_cast(float, u);
}
__device__ __forceinline__ f32x4 zero4() {
  f32x4 v; v.x = 0.f; v.y = 0.f; v.z = 0.f; v.w = 0.f; return v;
}
template <int CTRL>
__device__ __forceinline__ float dpp_add(float v) {
  int p = __builtin_amdgcn_update_dpp(0, __builtin_bit_cast(int, v),
                                      CTRL, 0xF, 0xF, true);
  return v + __builtin_bit_cast(float, p);
}
template <int CTRL>
__device__ __forceinline__ float dpp_mov(float v) {  // partner's value
  int p = __builtin_amdgcn_update_dpp(0, __builtin_bit_cast(int, v),
                                      CTRL, 0xF, 0xF, true);
  return __builtin_bit_cast(float, p);
}
__device__ __forceinline__ float red16(float v) {  // sum over 16-lane group
  v = dpp_add<0xB1>(v);    // xor1
  v = dpp_add<0x4E>(v);    // xor2
  v = dpp_add<0x141>(v);   // row_half_mirror
  v = dpp_add<0x140>(v);   // row_mirror
  return v;
}

// ---------------------------------------------------------------------------
// Weight prep: fp32 row-major W[K][N] -> bf16 MFMA-fragment order:
//   frag f = kc*(N/16) + ntile (kc = 32-wide K slab); 64 lanes x 8 elems:
//   lane reads B[n = ntile*16 + (lane&15)][k = kc*32 + (lane>>4)*8 + e].
// ws regions (bf16 elems): stem @0 ; blocks @16384,81920,147456 ; head @212992 ;
// Z buffer @262144 (1024*128*128).
// ---------------------------------------------------------------------------
__global__ void prep_weights(const float* __restrict__ Win, const float* __restrict__ Wb,
                             const float* __restrict__ Wout, unsigned short* __restrict__ ws) {
  int g = blockIdx.x * 256 + threadIdx.x;
  if (g >= 30720) return;
  const float* W; int N; int local;
  if (g < 2048) { W = Win; N = 256; local = g; }
  else if (g < 26624) {
    int i = g - 2048; int blk = i >> 13; local = i & 8191;
    W = Wb + blk * 65536; N = 256;
  } else { W = Wout; N = 128; local = g - 26624; }
  int f = local >> 6, lane = local & 63;
  int NTL = N >> 4;
  int kc = f / NTL, ntile = f - kc * NTL;
  int n = ntile * 16 + (lane & 15);
  int k0 = kc * 32 + (lane >> 4) * 8;
  unsigned short o[8];
#pragma unroll
  for (int e = 0; e < 8; ++e) o[e] = f2bf(W[(size_t)(k0 + e) * N + n]);
  *reinterpret_cast<uint4*>(ws + (size_t)g * 8) = *reinterpret_cast<uint4*>(o);
}

// ---------------------------------------------------------------------------
// One GEMM layer over 32 rows, 8 waves (wave = column group wc).
// Wave tile 32 x (16*NT); NT=2 for N=256, NT=1 for N=128.
// acc C-layout: row = 16*mt + 4*q + r, col = colbase + 16*nt + l16.
// MODE: 0 stem relu(ln) ; 1 residual (acc-domain register carry) ; 2 head ->
// z staged via Xb region then coalesced-copied to global Z.
// pt: current layer's 64-float stats buffer (s1[32], s2[32]); ptn: next
// layer's buffer, zeroed post-Bp (double-buffer race-freedom).
// Barriers: B1 (prev Xb stores visible) ; Bp (partials done + all waves'
// K-loop Xb reads done -> safe to overwrite Xb).
// ---------------------------------------------------------------------------
template <int KL, int N, int MODE>
__device__ __forceinline__ void layer(unsigned short* __restrict__ Xb,
                                      float* __restrict__ pt, float* __restrict__ ptn,
                                      const unsigned short* __restrict__ Wf,
                                      int tid, int wave, int lane,
                                      const float* __restrict__ bias,
                                      const float* __restrict__ gam,
                                      const float* __restrict__ bet,
                                      float (&xprev)[16],
                                      unsigned short* __restrict__ Z, size_t rowglob) {
  constexpr int NT = N / 128;        // frags per wave per k-slab
  constexpr int NTL = N / 16;        // 16-col tiles across N
  constexpr int KC = KL / 32;        // 32-wide K slabs
  const int wc = wave;               // 8 waves = 8 column groups
  const int q = lane >> 4, l16 = lane & 15;
  const int colbase = wc * 16 * NT;
  const unsigned short* Wl = Wf + lane * 8;

  // layer params for this lane's columns — issued before the K-loop so the
  // VMEM latency hides under it (consumed only after the K-loop).
  float bv[NT], gv[NT], ev[NT];
#pragma unroll
  for (int nt = 0; nt < NT; ++nt) {
    const int c = colbase + 16 * nt + l16;
    bv[nt] = bias[c]; gv[nt] = gam[c]; ev[nt] = bet[c];
  }

  f32x4 acc[2][NT];
#pragma unroll
  for (int mt = 0; mt < 2; ++mt)
#pragma unroll
    for (int nt = 0; nt < NT; ++nt) acc[mt][nt] = zero4();

  bf16x8 bcur[NT];
#pragma unroll
  for (int nt = 0; nt < NT; ++nt)    // prefetch slab 0 before the barrier
    bcur[nt] = *reinterpret_cast<const bf16x8*>(Wl + (size_t)(wc * NT + nt) * 512);

  __syncthreads();                   // B1: prev layer's Xb stores visible
#pragma unroll
  for (int kc = 0; kc < KC; ++kc) {
    bf16x8 bnext[NT];
    if (kc + 1 < KC) {
#pragma unroll
      for (int nt = 0; nt < NT; ++nt)
        bnext[nt] = *reinterpret_cast<const bf16x8*>(
            Wl + (size_t)((kc + 1) * NTL + wc * NT + nt) * 512);
    }
    const int kk = kc * 32 + q * 8;
    bf16x8 a0 = *reinterpret_cast<const bf16x8*>(Xb + (l16) * XB_STRIDE + kk);
    bf16x8 a1 = *reinterpret_cast<const bf16x8*>(Xb + (16 + l16) * XB_STRIDE + kk);
#pragma unroll
    for (int nt = 0; nt < NT; ++nt)
      acc[0][nt] = __builtin_amdgcn_mfma_f32_16x16x32_bf16(a0, bcur[nt], acc[0][nt], 0, 0, 0);
#pragma unroll
    for (int nt = 0; nt < NT; ++nt)
      acc[1][nt] = __builtin_amdgcn_mfma_f32_16x16x32_bf16(a1, bcur[nt], acc[1][nt], 0, 0, 0);
    if (kc + 1 < KC) {
#pragma unroll
      for (int nt = 0; nt < NT; ++nt) bcur[nt] = bnext[nt];
    }
  }

  // ---- bias into acc + per-row partial stats over the wave's cols
  float s1p[2][4], s2p[2][4];
#pragma unroll
  for (int mt = 0; mt < 2; ++mt)
#pragma unroll
    for (int r = 0; r < 4; ++r) {
      float a0 = acc[mt][0][r] + bv[0];
      acc[mt][0][r] = a0;
      float s1 = a0, s2 = a0 * a0;
      if constexpr (NT == 2) {
        float a1 = acc[mt][1][r] + bv[1];
        acc[mt][1][r] = a1;
        s1 += a1; s2 = __builtin_fmaf(a1, a1, s2);
      }
      s1p[mt][r] = red16(s1);          // sum over 16 lanes x NT cols
      s2p[mt][r] = red16(s2);
    }
  // cross-wave combine: one lane per (mt,r) per q-group adds its row partial
#pragma unroll
  for (int mt = 0; mt < 2; ++mt)
#pragma unroll
    for (int r = 0; r < 4; ++r) {
      if (l16 == mt * 4 + r) {
        const int row = 16 * mt + 4 * q + r;
        atomicAdd(&pt[row], s1p[mt][r]);
        atomicAdd(&pt[32 + row], s2p[mt][r]);
      }
    }
  __syncthreads();                   // Bp: partials complete; K-loop reads done

  // row totals (broadcast reads: all 16 lanes of a q-group read same addr)
  f32x4 t1a = *reinterpret_cast<const f32x4*>(pt + 4 * q);
  f32x4 t1b = *reinterpret_cast<const f32x4*>(pt + 16 + 4 * q);
  f32x4 t2a = *reinterpret_cast<const f32x4*>(pt + 32 + 4 * q);
  f32x4 t2b = *reinterpret_cast<const f32x4*>(pt + 48 + 4 * q);
  if (tid < 64) ptn[tid] = 0.f;      // zero next layer's buffer (safe window)
  constexpr float inv = 1.0f / N;
  float rstd[2][4], nmr[2][4];
#pragma unroll
  for (int mt = 0; mt < 2; ++mt)
#pragma unroll
    for (int r = 0; r < 4; ++r) {
      const float tt1 = mt ? t1b[r] : t1a[r];
      const float tt2 = mt ? t2b[r] : t2a[r];
      const float mu = tt1 * inv;
      const float var = __builtin_fmaf(tt2, inv, -mu * mu);
      const float rs = rsqrtf(var + 1e-5f);
      rstd[mt][r] = rs; nmr[mt][r] = -mu * rs;
    }

  // ---- normalize acc in regs, relu+residual, DPP-pack bf16 pairs, store
  unsigned int* Xw = reinterpret_cast<unsigned int*>(Xb);
#pragma unroll
  for (int mt = 0; mt < 2; ++mt)
#pragma unroll
    for (int r = 0; r < 4; ++r) {
      const int row = 16 * mt + 4 * q + r;
      unsigned int ures[NT];
#pragma unroll
      for (int nt = 0; nt < NT; ++nt) {
        const int e = mt * 8 + nt * 4 + r;
        float t = __builtin_fmaf(acc[mt][nt][r], rstd[mt][r], nmr[mt][r]);
        float o = __builtin_fmaf(t, gv[nt], ev[nt]);
        float xv;
        if constexpr (MODE == 0) { xv = fmaxf(o, 0.f); xprev[e] = xv; }
        else if constexpr (MODE == 1) { xv = xprev[e] + fmaxf(o, 0.f); xprev[e] = xv; }
        else { xv = o; (void)e; }
        // lane pair (l16, l16^1) holds adjacent cols -> pack one u32
        float pv = dpp_mov<0xB1>(xv);          // quad_perm xor1 partner
        float lo = (l16 & 1) ? pv : xv;
        float hi = (l16 & 1) ? xv : pv;
        ures[nt] = __builtin_amdgcn_perm(rne16(hi), rne16(lo), 0x07060302);
      }
      if constexpr (MODE != 2) {
        // even lanes write the n=0 pair, odd lanes the n=1 pair (2-way banks)
        const unsigned int u = (l16 & 1) ? ures[NT - 1] : ures[0];
        const int idxu = 16 * wc + ((l16 & 1) ? 8 + (l16 >> 1) : (l16 >> 1));
        Xw[row * 132 + idxu] = u;
      } else {
        // head (NT=1): stage packed z into Xb region, stride 68 u32 (16B-align)
        if (!(l16 & 1)) Xw[row * 68 + 8 * wc + (l16 >> 1)] = ures[0];
      }
    }
  if constexpr (MODE == 2) {
    __syncthreads();                 // staging complete
    const int rr = tid >> 4, cc = (tid & 15) * 4;   // 32 rows x 64 u32
    uint4 v = *reinterpret_cast<const uint4*>(Xw + rr * 68 + cc);
    *reinterpret_cast<uint4*>(Z + (rowglob + rr) * 128 + cc * 2) = v;
  }
}

// ---------------------------------------------------------------------------
// Kernel 1: ResNetMLP over 32 rows (quarter graph). 4096 blocks x 512 thr.
// waves_per_eu(6): 85-reg unified budget, 3 blocks/CU (R15-verified 60%).
// ---------------------------------------------------------------------------
__global__ __attribute__((amdgpu_flat_work_group_size(512, 512), amdgpu_waves_per_eu(6)))
void mlp_main(const float* __restrict__ H, const unsigned short* __restrict__ ws,
              const float* __restrict__ b_in, const float* __restrict__ g_in,
              const float* __restrict__ beta_in,
              const float* __restrict__ bb, const float* __restrict__ gb,
              const float* __restrict__ betab,
              const float* __restrict__ b_out, const float* __restrict__ g_out,
              const float* __restrict__ beta_out,
              unsigned short* __restrict__ Z) {
  extern __shared__ char smem[];
  unsigned short* Xb = (unsigned short*)smem;
  float* ptb = (float*)(smem + LDS_PT);   // 2 x 64-float stats buffers
  const int tid = threadIdx.x;
  const int wave = tid >> 6, lane = tid & 63;
  const size_t rowglob = (size_t)blockIdx.x * 32;

  // stage H (32 x 64 fp32) -> Xb bf16 ; zero both stats buffers
  {
    int row = tid >> 4, c4 = (tid & 15) * 4;
    float4 f = *reinterpret_cast<const float4*>(H + (rowglob + row) * 64 + c4);
    uint2 o;
    o.x = __builtin_amdgcn_perm(rne16(f.y), rne16(f.x), 0x07060302);
    o.y = __builtin_amdgcn_perm(rne16(f.w), rne16(f.z), 0x07060302);
    *reinterpret_cast<uint2*>(Xb + row * XB_STRIDE + c4) = o;
    if (tid < 128) ptb[tid] = 0.f;
  }

  float xprev[16];
  layer<64, 256, 0>(Xb, ptb,      ptb + 64, ws,           tid, wave, lane, b_in,     g_in,     beta_in,     xprev, Z, rowglob);
  layer<256, 256, 1>(Xb, ptb + 64, ptb,      ws + 16384,  tid, wave, lane, bb,       gb,       betab,       xprev, Z, rowglob);
  layer<256, 256, 1>(Xb, ptb,      ptb + 64, ws + 81920,  tid, wave, lane, bb + 256, gb + 256, betab + 256, xprev, Z, rowglob);
  layer<256, 256, 1>(Xb, ptb + 64, ptb,      ws + 147456, tid, wave, lane, bb + 512, gb + 512, betab + 512, xprev, Z, rowglob);
  layer<256, 128, 2>(Xb, ptb,      ptb + 64, ws + 212992, tid, wave, lane, b_out,    g_out,    beta_out,    xprev, Z, rowglob);
}

// ---------------------------------------------------------------------------
// Kernel 2: per-graph gram + mean-distance + softmax + weighted pool.
// 1024 blocks x 512 thr; Z[g] (128x128 bf16) staged to LDS. (R7-verified.)
// ---------------------------------------------------------------------------
__global__ __attribute__((amdgpu_flat_work_group_size(512, 512)))
void pool_main(const unsigned short* __restrict__ Z, float* __restrict__ out) {
  __shared__ unsigned short Zb[128 * ZB_STRIDE];
  __shared__ float sqv[128], sm[128], smw[128];
  const int tid = threadIdx.x;
  const int g = blockIdx.x;
  const int wave = tid >> 6, lane = tid & 63;
  const int q = lane >> 4, l16 = lane & 15;

  {
    int zr = tid >> 2, zc = (tid & 3) * 32;
    const uint4* zp = reinterpret_cast<const uint4*>(Z + ((size_t)g * 128 + zr) * 128 + zc);
    uint4* zd = reinterpret_cast<uint4*>(Zb + zr * ZB_STRIDE + zc);
    zd[0] = zp[0]; zd[1] = zp[1]; zd[2] = zp[2]; zd[3] = zp[3];
  }
  __syncthreads();

  // gram G = Z Z^T : wave owns 16 rows x 128 cols
  f32x4 g2[8];
#pragma unroll
  for (int nt = 0; nt < 8; ++nt) g2[nt] = zero4();
#pragma unroll
  for (int ks = 0; ks < 4; ++ks) {
    int kk = ks * 32 + q * 8;
    bf16x8 a = *reinterpret_cast<const bf16x8*>(Zb + (16 * wave + l16) * ZB_STRIDE + kk);
#pragma unroll
    for (int nt = 0; nt < 8; ++nt) {
      bf16x8 bfr = *reinterpret_cast<const bf16x8*>(Zb + (16 * nt + l16) * ZB_STRIDE + kk);
      g2[nt] = __builtin_amdgcn_mfma_f32_16x16x32_bf16(a, bfr, g2[nt], 0, 0, 0);
    }
  }
  // publish sq_i = G_ii (diag) so d_ii == sqrt(1e-12) exactly like ref
  if ((l16 >> 2) == q) {
#pragma unroll
    for (int nt = 0; nt < 8; ++nt)
      if (nt == wave) {
#pragma unroll
        for (int r = 0; r < 4; ++r)
          if ((l16 & 3) == r) sqv[16 * wave + l16] = g2[nt][r];
      }
  }
  __syncthreads();
  // distances and s_i = mean_j d_ij
  float sqi[4];
#pragma unroll
  for (int r = 0; r < 4; ++r) sqi[r] = sqv[16 * wave + q * 4 + r];
  float sp[4] = {0.f, 0.f, 0.f, 0.f};
#pragma unroll
  for (int nt = 0; nt < 8; ++nt) {
    float sqj = sqv[16 * nt + l16];
#pragma unroll
    for (int r = 0; r < 4; ++r) {
      float d2 = sqi[r] + sqj - 2.0f * g2[nt][r];
      sp[r] += sqrtf(fmaxf(d2, 0.f) + 1e-12f);
    }
  }
#pragma unroll
  for (int d = 1; d < 16; d <<= 1) {
#pragma unroll
    for (int r = 0; r < 4; ++r) { float t = sp[r]; t += __shfl_xor(t, d); sp[r] = t; }
  }
  if (l16 == 0) {
#pragma unroll
    for (int r = 0; r < 4; ++r) sm[16 * wave + q * 4 + r] = sp[r] * (1.0f / 128.0f);
  }
  __syncthreads();
  // softmax(s/TAU) by wave 0 (1/TAU = 4)
  if (wave == 0) {
    float l0 = sm[lane] * 4.0f;
    float l1 = sm[lane + 64] * 4.0f;
    float mx = fmaxf(l0, l1);
#pragma unroll
    for (int d = 1; d < 64; d <<= 1) mx = fmaxf(mx, __shfl_xor(mx, d));
    float e0 = __expf(l0 - mx), e1 = __expf(l1 - mx);
    float ss = e0 + e1;
#pragma unroll
    for (int d = 1; d < 64; d <<= 1) ss += __shfl_xor(ss, d);
    float inv = 1.0f / ss;
    float w0 = e0 * inv, w1 = e1 * inv;
    smw[lane] = w0;
    smw[lane + 64] = w1;
    out[131072 + g * 128 + lane] = w0;
    out[131072 + g * 128 + 64 + lane] = w1;
  }
  __syncthreads();
  // v_loc = sum_i w_i * Z[i,:]
  {
    int c = 16 * wave + l16;
    float acv = 0.f;
#pragma unroll
    for (int i0 = 0; i0 < 32; ++i0) {
      int i = q * 32 + i0;
      acv += smw[i] * bf2f(Zb[i * ZB_STRIDE + c]);
    }
    acv += __shfl_xor(acv, 16);
    acv += __shfl_xor(acv, 32);
    if (q == 0) out[g * 128 + c] = acv;
  }
}

// ---------------------------------------------------------------------------
extern "C" void kernel_launch(void* const* d_in, const int* in_sizes, int n_in,
                              void* d_out, int out_size, void* d_ws, size_t ws_size,
                              hipStream_t stream) {
  (void)in_sizes; (void)n_in; (void)out_size; (void)ws_size;
  const float* H        = (const float*)d_in[0];
  // d_in[1] = batch_ptr (uniform 128/graph, unused)
  const float* W_in     = (const float*)d_in[2];
  const float* b_in     = (const float*)d_in[3];
  const float* g_in     = (const float*)d_in[4];
  const float* beta_in  = (const float*)d_in[5];
  const float* Wb       = (const float*)d_in[6];
  const float* bb       = (const float*)d_in[7];
  const float* gb       = (const float*)d_in[8];
  const float* betab    = (const float*)d_in[9];
  const float* W_out    = (const float*)d_in[10];
  const float* b_out    = (const float*)d_in[11];
  const float* g_out    = (const float*)d_in[12];
  const float* beta_out = (const float*)d_in[13];
  float* out = (float*)d_out;
  unsigned short* ws = (unsigned short*)d_ws;
  unsigned short* Z = ws + 262144;      // 1024*128*128 bf16 = 33.5 MB

  prep_weights<<<120, 256, 0, stream>>>(W_in, Wb, W_out, ws);
  mlp_main<<<4096, 512, LDS_TOTAL, stream>>>(H, ws, b_in, g_in, beta_in,
                                             bb, gb, betab, b_out, g_out, beta_out, Z);
  pool_main<<<1024, 512, 0, stream>>>(Z, out);
}

// Round 8
// 270.369 us; speedup vs baseline: 1.0891x; 1.0891x over previous
//
#include <hip/hip_runtime.h>
#include <stdint.h>

// ---------------------------------------------------------------------------
// LocalBranch: ResNetMLP (5x GEMM+LN) + per-graph distance softmax pool.
// R18 = R17 (in-register LN) + waves_per_eu(4) + fused stats atomics.
//     R17 post-mortem: structure correct (passed; bank conflicts 11.3M->9.0M,
//     barriers 4->2, LDS 36->17KB) but acc[16] now lives K-loop->normalize,
//     pushing demand ~103 regs > the 85 budget of waves_per_eu(6) -> 18
//     dwords/thread scratch (WRITE 180MB, FETCH 78MB) -> mlp 207us.
//     Fix: budget 128 (waves_per_eu 4; R13/R14-proven spill-free) and remove
//     the s1p/s2p[2][4] arrays by fusing red16+atomicAdd per (mt,r) (-16
//     regs). 2 blocks/CU static; this structure does ~half the non-MFMA
//     work of R14's at the same occupancy.
// R17: per-layer flow: K-loop -> bias in acc -> red16 row partials ->
//     ds atomics into 64-float pt (double-buffered) -> ONE barrier -> lanes
//     read row totals, rstd/nmr, normalize acc in regs, relu+residual
//     (xprev acc-domain), DPP-pair bf16 pack, store next Xb. Head stages z
//     via freed Xb region for coalesced Z stores.
// R14: 512-thr blocks (32 rows, 8 waves, 4096 blocks) (kept).
// ---------------------------------------------------------------------------

typedef __attribute__((ext_vector_type(8))) short bf16x8;   // 8 bf16 = 4 VGPRs
typedef __attribute__((ext_vector_type(4))) float f32x4;

#define XB_STRIDE 264            // bf16 elems; 132 dwords/row
#define ZB_STRIDE 136            // pool Z tile 128+8
#define LDS_PT    16896          // byte offset: pt after Xb (32*264*2); 16B-aligned
#define LDS_TOTAL 17408          // + 2*64 floats

__device__ __forceinline__ unsigned int rne16(float f) {
  unsigned int u = __builtin_bit_cast(unsigned int, f);
  return u + 0x7fffu + ((u >> 16) & 1u);     // RNE bf16 in high 16 bits
}
__device__ __forceinline__ unsigned short f2bf(float f) {
  return (unsigned short)(rne16(f) >> 16);
}
__device__ __forceinline__ float bf2f(unsigned short h) {
  unsigned int u = ((unsigned int)h) << 16;
  return __builtin_bit_cast(float, u);
}
__device__ __forceinline__ f32x4 zero4() {
  f32x4 v; v.x = 0.f; v.y = 0.f; v.z = 0.f; v.w = 0.f; return v;
}
template <int CTRL>
__device__ __forceinline__ float dpp_add(float v) {
  int p = __builtin_amdgcn_update_dpp(0, __builtin_bit_cast(int, v),
                                      CTRL, 0xF, 0xF, true);
  return v + __builtin_bit_cast(float, p);
}
template <int CTRL>
__device__ __forceinline__ float dpp_mov(float v) {  // partner's value
  int p = __builtin_amdgcn_update_dpp(0, __builtin_bit_cast(int, v),
                                      CTRL, 0xF, 0xF, true);
  return __builtin_bit_cast(float, p);
}
__device__ __forceinline__ float red16(float v) {  // sum over 16-lane group
  v = dpp_add<0xB1>(v);    // xor1
  v = dpp_add<0x4E>(v);    // xor2
  v = dpp_add<0x141>(v);   // row_half_mirror
  v = dpp_add<0x140>(v);   // row_mirror
  return v;
}

// ---------------------------------------------------------------------------
// Weight prep: fp32 row-major W[K][N] -> bf16 MFMA-fragment order:
//   frag f = kc*(N/16) + ntile (kc = 32-wide K slab); 64 lanes x 8 elems:
//   lane reads B[n = ntile*16 + (lane&15)][k = kc*32 + (lane>>4)*8 + e].
// ws regions (bf16 elems): stem @0 ; blocks @16384,81920,147456 ; head @212992 ;
// Z buffer @262144 (1024*128*128).
// ---------------------------------------------------------------------------
__global__ void prep_weights(const float* __restrict__ Win, const float* __restrict__ Wb,
                             const float* __restrict__ Wout, unsigned short* __restrict__ ws) {
  int g = blockIdx.x * 256 + threadIdx.x;
  if (g >= 30720) return;
  const float* W; int N; int local;
  if (g < 2048) { W = Win; N = 256; local = g; }
  else if (g < 26624) {
    int i = g - 2048; int blk = i >> 13; local = i & 8191;
    W = Wb + blk * 65536; N = 256;
  } else { W = Wout; N = 128; local = g - 26624; }
  int f = local >> 6, lane = local & 63;
  int NTL = N >> 4;
  int kc = f / NTL, ntile = f - kc * NTL;
  int n = ntile * 16 + (lane & 15);
  int k0 = kc * 32 + (lane >> 4) * 8;
  unsigned short o[8];
#pragma unroll
  for (int e = 0; e < 8; ++e) o[e] = f2bf(W[(size_t)(k0 + e) * N + n]);
  *reinterpret_cast<uint4*>(ws + (size_t)g * 8) = *reinterpret_cast<uint4*>(o);
}

// ---------------------------------------------------------------------------
// One GEMM layer over 32 rows, 8 waves (wave = column group wc).
// Wave tile 32 x (16*NT); NT=2 for N=256, NT=1 for N=128.
// acc C-layout: row = 16*mt + 4*q + r, col = colbase + 16*nt + l16.
// MODE: 0 stem relu(ln) ; 1 residual (acc-domain register carry) ; 2 head ->
// z staged via Xb region then coalesced-copied to global Z.
// pt: current layer's 64-float stats buffer (s1[32], s2[32]); ptn: next
// layer's buffer, zeroed post-Bp (double-buffer race-freedom).
// Barriers: B1 (prev Xb stores visible) ; Bp (partials done + all waves'
// K-loop Xb reads done -> safe to overwrite Xb).
// ---------------------------------------------------------------------------
template <int KL, int N, int MODE>
__device__ __forceinline__ void layer(unsigned short* __restrict__ Xb,
                                      float* __restrict__ pt, float* __restrict__ ptn,
                                      const unsigned short* __restrict__ Wf,
                                      int tid, int wave, int lane,
                                      const float* __restrict__ bias,
                                      const float* __restrict__ gam,
                                      const float* __restrict__ bet,
                                      float (&xprev)[16],
                                      unsigned short* __restrict__ Z, size_t rowglob) {
  constexpr int NT = N / 128;        // frags per wave per k-slab
  constexpr int NTL = N / 16;        // 16-col tiles across N
  constexpr int KC = KL / 32;        // 32-wide K slabs
  const int wc = wave;               // 8 waves = 8 column groups
  const int q = lane >> 4, l16 = lane & 15;
  const int colbase = wc * 16 * NT;
  const unsigned short* Wl = Wf + lane * 8;

  // layer params for this lane's columns — issued before the K-loop so the
  // VMEM latency hides under it (consumed only after the K-loop).
  float bv[NT], gv[NT], ev[NT];
#pragma unroll
  for (int nt = 0; nt < NT; ++nt) {
    const int c = colbase + 16 * nt + l16;
    bv[nt] = bias[c]; gv[nt] = gam[c]; ev[nt] = bet[c];
  }

  f32x4 acc[2][NT];
#pragma unroll
  for (int mt = 0; mt < 2; ++mt)
#pragma unroll
    for (int nt = 0; nt < NT; ++nt) acc[mt][nt] = zero4();

  bf16x8 bcur[NT];
#pragma unroll
  for (int nt = 0; nt < NT; ++nt)    // prefetch slab 0 before the barrier
    bcur[nt] = *reinterpret_cast<const bf16x8*>(Wl + (size_t)(wc * NT + nt) * 512);

  __syncthreads();                   // B1: prev layer's Xb stores visible
#pragma unroll
  for (int kc = 0; kc < KC; ++kc) {
    bf16x8 bnext[NT];
    if (kc + 1 < KC) {
#pragma unroll
      for (int nt = 0; nt < NT; ++nt)
        bnext[nt] = *reinterpret_cast<const bf16x8*>(
            Wl + (size_t)((kc + 1) * NTL + wc * NT + nt) * 512);
    }
    const int kk = kc * 32 + q * 8;
    bf16x8 a0 = *reinterpret_cast<const bf16x8*>(Xb + (l16) * XB_STRIDE + kk);
    bf16x8 a1 = *reinterpret_cast<const bf16x8*>(Xb + (16 + l16) * XB_STRIDE + kk);
#pragma unroll
    for (int nt = 0; nt < NT; ++nt)
      acc[0][nt] = __builtin_amdgcn_mfma_f32_16x16x32_bf16(a0, bcur[nt], acc[0][nt], 0, 0, 0);
#pragma unroll
    for (int nt = 0; nt < NT; ++nt)
      acc[1][nt] = __builtin_amdgcn_mfma_f32_16x16x32_bf16(a1, bcur[nt], acc[1][nt], 0, 0, 0);
    if (kc + 1 < KC) {
#pragma unroll
      for (int nt = 0; nt < NT; ++nt) bcur[nt] = bnext[nt];
    }
  }

  // ---- bias into acc + per-row stats: red16 fused with guarded LDS atomic
  // (no partial arrays: only 2 scalar transients live per (mt,r) step)
#pragma unroll
  for (int mt = 0; mt < 2; ++mt)
#pragma unroll
    for (int r = 0; r < 4; ++r) {
      float a0 = acc[mt][0][r] + bv[0];
      acc[mt][0][r] = a0;
      float s1 = a0, s2 = a0 * a0;
      if constexpr (NT == 2) {
        float a1 = acc[mt][1][r] + bv[1];
        acc[mt][1][r] = a1;
        s1 += a1; s2 = __builtin_fmaf(a1, a1, s2);
      }
      s1 = red16(s1);                // sum over 16 lanes x NT cols
      s2 = red16(s2);
      if (l16 == mt * 4 + r) {
        const int row = 16 * mt + 4 * q + r;
        atomicAdd(&pt[row], s1);
        atomicAdd(&pt[32 + row], s2);
      }
    }
  __syncthreads();                   // Bp: partials complete; K-loop reads done

  // row totals (broadcast reads: all 16 lanes of a q-group read same addr)
  f32x4 t1a = *reinterpret_cast<const f32x4*>(pt + 4 * q);
  f32x4 t1b = *reinterpret_cast<const f32x4*>(pt + 16 + 4 * q);
  f32x4 t2a = *reinterpret_cast<const f32x4*>(pt + 32 + 4 * q);
  f32x4 t2b = *reinterpret_cast<const f32x4*>(pt + 48 + 4 * q);
  if (tid < 64) ptn[tid] = 0.f;      // zero next layer's buffer (safe window)
  constexpr float inv = 1.0f / N;
  float rstd[2][4], nmr[2][4];
#pragma unroll
  for (int mt = 0; mt < 2; ++mt)
#pragma unroll
    for (int r = 0; r < 4; ++r) {
      const float tt1 = mt ? t1b[r] : t1a[r];
      const float tt2 = mt ? t2b[r] : t2a[r];
      const float mu = tt1 * inv;
      const float var = __builtin_fmaf(tt2, inv, -mu * mu);
      const float rs = rsqrtf(var + 1e-5f);
      rstd[mt][r] = rs; nmr[mt][r] = -mu * rs;
    }

  // ---- normalize acc in regs, relu+residual, DPP-pack bf16 pairs, store
  unsigned int* Xw = reinterpret_cast<unsigned int*>(Xb);
#pragma unroll
  for (int mt = 0; mt < 2; ++mt)
#pragma unroll
    for (int r = 0; r < 4; ++r) {
      const int row = 16 * mt + 4 * q + r;
      unsigned int ures[NT];
#pragma unroll
      for (int nt = 0; nt < NT; ++nt) {
        const int e = mt * 8 + nt * 4 + r;
        float t = __builtin_fmaf(acc[mt][nt][r], rstd[mt][r], nmr[mt][r]);
        float o = __builtin_fmaf(t, gv[nt], ev[nt]);
        float xv;
        if constexpr (MODE == 0) { xv = fmaxf(o, 0.f); xprev[e] = xv; }
        else if constexpr (MODE == 1) { xv = xprev[e] + fmaxf(o, 0.f); xprev[e] = xv; }
        else { xv = o; (void)e; }
        // lane pair (l16, l16^1) holds adjacent cols -> pack one u32
        float pv = dpp_mov<0xB1>(xv);          // quad_perm xor1 partner
        float lo = (l16 & 1) ? pv : xv;
        float hi = (l16 & 1) ? xv : pv;
        ures[nt] = __builtin_amdgcn_perm(rne16(hi), rne16(lo), 0x07060302);
      }
      if constexpr (MODE != 2) {
        // even lanes write the n=0 pair, odd lanes the n=1 pair (2-way banks)
        const unsigned int u = (l16 & 1) ? ures[NT - 1] : ures[0];
        const int idxu = 16 * wc + ((l16 & 1) ? 8 + (l16 >> 1) : (l16 >> 1));
        Xw[row * 132 + idxu] = u;
      } else {
        // head (NT=1): stage packed z into Xb region, stride 68 u32 (16B-align)
        if (!(l16 & 1)) Xw[row * 68 + 8 * wc + (l16 >> 1)] = ures[0];
      }
    }
  if constexpr (MODE == 2) {
    __syncthreads();                 // staging complete
    const int rr = tid >> 4, cc = (tid & 15) * 4;   // 32 rows x 64 u32
    uint4 v = *reinterpret_cast<const uint4*>(Xw + rr * 68 + cc);
    *reinterpret_cast<uint4*>(Z + (rowglob + rr) * 128 + cc * 2) = v;
  }
}

// ---------------------------------------------------------------------------
// Kernel 1: ResNetMLP over 32 rows (quarter graph). 4096 blocks x 512 thr.
// waves_per_eu(4): 128-reg budget (R13/R14-proven spill-free), 2 blocks/CU.
// ---------------------------------------------------------------------------
__global__ __attribute__((amdgpu_flat_work_group_size(512, 512), amdgpu_waves_per_eu(4)))
void mlp_main(const float* __restrict__ H, const unsigned short* __restrict__ ws,
              const float* __restrict__ b_in, const float* __restrict__ g_in,
              const float* __restrict__ beta_in,
              const float* __restrict__ bb, const float* __restrict__ gb,
              const float* __restrict__ betab,
              const float* __restrict__ b_out, const float* __restrict__ g_out,
              const float* __restrict__ beta_out,
              unsigned short* __restrict__ Z) {
  extern __shared__ char smem[];
  unsigned short* Xb = (unsigned short*)smem;
  float* ptb = (float*)(smem + LDS_PT);   // 2 x 64-float stats buffers
  const int tid = threadIdx.x;
  const int wave = tid >> 6, lane = tid & 63;
  const size_t rowglob = (size_t)blockIdx.x * 32;

  // stage H (32 x 64 fp32) -> Xb bf16 ; zero both stats buffers
  {
    int row = tid >> 4, c4 = (tid & 15) * 4;
    float4 f = *reinterpret_cast<const float4*>(H + (rowglob + row) * 64 + c4);
    uint2 o;
    o.x = __builtin_amdgcn_perm(rne16(f.y), rne16(f.x), 0x07060302);
    o.y = __builtin_amdgcn_perm(rne16(f.w), rne16(f.z), 0x07060302);
    *reinterpret_cast<uint2*>(Xb + row * XB_STRIDE + c4) = o;
    if (tid < 128) ptb[tid] = 0.f;
  }

  float xprev[16];
  layer<64, 256, 0>(Xb, ptb,      ptb + 64, ws,           tid, wave, lane, b_in,     g_in,     beta_in,     xprev, Z, rowglob);
  layer<256, 256, 1>(Xb, ptb + 64, ptb,      ws + 16384,  tid, wave, lane, bb,       gb,       betab,       xprev, Z, rowglob);
  layer<256, 256, 1>(Xb, ptb,      ptb + 64, ws + 81920,  tid, wave, lane, bb + 256, gb + 256, betab + 256, xprev, Z, rowglob);
  layer<256, 256, 1>(Xb, ptb + 64, ptb,      ws + 147456, tid, wave, lane, bb + 512, gb + 512, betab + 512, xprev, Z, rowglob);
  layer<256, 128, 2>(Xb, ptb,      ptb + 64, ws + 212992, tid, wave, lane, b_out,    g_out,    beta_out,    xprev, Z, rowglob);
}

// ---------------------------------------------------------------------------
// Kernel 2: per-graph gram + mean-distance + softmax + weighted pool.
// 1024 blocks x 512 thr; Z[g] (128x128 bf16) staged to LDS. (R7-verified.)
// ---------------------------------------------------------------------------
__global__ __attribute__((amdgpu_flat_work_group_size(512, 512)))
void pool_main(const unsigned short* __restrict__ Z, float* __restrict__ out) {
  __shared__ unsigned short Zb[128 * ZB_STRIDE];
  __shared__ float sqv[128], sm[128], smw[128];
  const int tid = threadIdx.x;
  const int g = blockIdx.x;
  const int wave = tid >> 6, lane = tid & 63;
  const int q = lane >> 4, l16 = lane & 15;

  {
    int zr = tid >> 2, zc = (tid & 3) * 32;
    const uint4* zp = reinterpret_cast<const uint4*>(Z + ((size_t)g * 128 + zr) * 128 + zc);
    uint4* zd = reinterpret_cast<uint4*>(Zb + zr * ZB_STRIDE + zc);
    zd[0] = zp[0]; zd[1] = zp[1]; zd[2] = zp[2]; zd[3] = zp[3];
  }
  __syncthreads();

  // gram G = Z Z^T : wave owns 16 rows x 128 cols
  f32x4 g2[8];
#pragma unroll
  for (int nt = 0; nt < 8; ++nt) g2[nt] = zero4();
#pragma unroll
  for (int ks = 0; ks < 4; ++ks) {
    int kk = ks * 32 + q * 8;
    bf16x8 a = *reinterpret_cast<const bf16x8*>(Zb + (16 * wave + l16) * ZB_STRIDE + kk);
#pragma unroll
    for (int nt = 0; nt < 8; ++nt) {
      bf16x8 bfr = *reinterpret_cast<const bf16x8*>(Zb + (16 * nt + l16) * ZB_STRIDE + kk);
      g2[nt] = __builtin_amdgcn_mfma_f32_16x16x32_bf16(a, bfr, g2[nt], 0, 0, 0);
    }
  }
  // publish sq_i = G_ii (diag) so d_ii == sqrt(1e-12) exactly like ref
  if ((l16 >> 2) == q) {
#pragma unroll
    for (int nt = 0; nt < 8; ++nt)
      if (nt == wave) {
#pragma unroll
        for (int r = 0; r < 4; ++r)
          if ((l16 & 3) == r) sqv[16 * wave + l16] = g2[nt][r];
      }
  }
  __syncthreads();
  // distances and s_i = mean_j d_ij
  float sqi[4];
#pragma unroll
  for (int r = 0; r < 4; ++r) sqi[r] = sqv[16 * wave + q * 4 + r];
  float sp[4] = {0.f, 0.f, 0.f, 0.f};
#pragma unroll
  for (int nt = 0; nt < 8; ++nt) {
    float sqj = sqv[16 * nt + l16];
#pragma unroll
    for (int r = 0; r < 4; ++r) {
      float d2 = sqi[r] + sqj - 2.0f * g2[nt][r];
      sp[r] += sqrtf(fmaxf(d2, 0.f) + 1e-12f);
    }
  }
#pragma unroll
  for (int d = 1; d < 16; d <<= 1) {
#pragma unroll
    for (int r = 0; r < 4; ++r) { float t = sp[r]; t += __shfl_xor(t, d); sp[r] = t; }
  }
  if (l16 == 0) {
#pragma unroll
    for (int r = 0; r < 4; ++r) sm[16 * wave + q * 4 + r] = sp[r] * (1.0f / 128.0f);
  }
  __syncthreads();
  // softmax(s/TAU) by wave 0 (1/TAU = 4)
  if (wave == 0) {
    float l0 = sm[lane] * 4.0f;
    float l1 = sm[lane + 64] * 4.0f;
    float mx = fmaxf(l0, l1);
#pragma unroll
    for (int d = 1; d < 64; d <<= 1) mx = fmaxf(mx, __shfl_xor(mx, d));
    float e0 = __expf(l0 - mx), e1 = __expf(l1 - mx);
    float ss = e0 + e1;
#pragma unroll
    for (int d = 1; d < 64; d <<= 1) ss += __shfl_xor(ss, d);
    float inv = 1.0f / ss;
    float w0 = e0 * inv, w1 = e1 * inv;
    smw[lane] = w0;
    smw[lane + 64] = w1;
    out[131072 + g * 128 + lane] = w0;
    out[131072 + g * 128 + 64 + lane] = w1;
  }
  __syncthreads();
  // v_loc = sum_i w_i * Z[i,:]
  {
    int c = 16 * wave + l16;
    float acv = 0.f;
#pragma unroll
    for (int i0 = 0; i0 < 32; ++i0) {
      int i = q * 32 + i0;
      acv += smw[i] * bf2f(Zb[i * ZB_STRIDE + c]);
    }
    acv += __shfl_xor(acv, 16);
    acv += __shfl_xor(acv, 32);
    if (q == 0) out[g * 128 + c] = acv;
  }
}

// ---------------------------------------------------------------------------
extern "C" void kernel_launch(void* const* d_in, const int* in_sizes, int n_in,
                              void* d_out, int out_size, void* d_ws, size_t ws_size,
                              hipStream_t stream) {
  (void)in_sizes; (void)n_in; (void)out_size; (void)ws_size;
  const float* H        = (const float*)d_in[0];
  // d_in[1] = batch_ptr (uniform 128/graph, unused)
  const float* W_in     = (const float*)d_in[2];
  const float* b_in     = (const float*)d_in[3];
  const float* g_in     = (const float*)d_in[4];
  const float* beta_in  = (const float*)d_in[5];
  const float* Wb       = (const float*)d_in[6];
  const float* bb       = (const float*)d_in[7];
  const float* gb       = (const float*)d_in[8];
  const float* betab    = (const float*)d_in[9];
  const float* W_out    = (const float*)d_in[10];
  const float* b_out    = (const float*)d_in[11];
  const float* g_out    = (const float*)d_in[12];
  const float* beta_out = (const float*)d_in[13];
  float* out = (float*)d_out;
  unsigned short* ws = (unsigned short*)d_ws;
  unsigned short* Z = ws + 262144;      // 1024*128*128 bf16 = 33.5 MB

  prep_weights<<<120, 256, 0, stream>>>(W_in, Wb, W_out, ws);
  mlp_main<<<4096, 512, LDS_TOTAL, stream>>>(H, ws, b_in, g_in, beta_in,
                                             bb, gb, betab, b_out, g_out, beta_out, Z);
  pool_main<<<1024, 512, 0, stream>>>(Z, out);
}

// Round 9
// 209.705 us; speedup vs baseline: 1.4042x; 1.2893x over previous
//
#include <hip/hip_runtime.h>
#include <stdint.h>

// ---------------------------------------------------------------------------
// LocalBranch: ResNetMLP (5x GEMM+LN) + per-graph distance softmax pool.
// R19: back to R14's Yb-transpose structure (R17/R18 in-register LN verdict:
//     VALU-bound — 16 red16/thread/layer pushed VALUBusy to 66%, mlp 189us;
//     abandoned). New lever: weight amortization. R14's 32-row blocks re-read
//     the full 491KB weight set per block -> 2.0GB L2 traffic (~58us at
//     34.5TB/s). R19: 64-row blocks, SAME 512 threads, wave runs a 4-M-tile
//     K-loop (acc[4][NT], 64 MFMA/layer) -> 1.0GB (~29us floor), 2x MFMA per
//     barrier. Residency: 2 blocks x 8 waves = 4 waves/SIMD -> 128 regs/wave
//     at waves_per_eu(4); demand ~122. LDS: Xb(33.8K) alias Yb(66.6K) + par
//     3K = 69.6KB -> 2 blocks/CU (needs hipFuncSetAttribute).
//     Phase B = two R14-style passes (rows +0,+32), streaming form.
// R11-R14: Xb/Yb alias barriers (B1/X1/B2/X2), swizzled phase-B map,
//     512-thr blocks, waves_per_eu(4) proven spill-free at this budget.
// ---------------------------------------------------------------------------

typedef __attribute__((ext_vector_type(8))) short bf16x8;   // 8 bf16 = 4 VGPRs
typedef __attribute__((ext_vector_type(4))) float f32x4;

#define XB_STRIDE 264            // bf16 elems; 132 dwords/row
#define YB_STRIDE 260            // fp32; row step == 4 banks
#define ZB_STRIDE 136            // pool Z tile 128+8
#define LDS_PAR   66560          // byte offset: par after Yb (64*260*4)
#define LDS_TOTAL 69632          // 66560 + 768*4

__device__ __forceinline__ unsigned int rne16(float f) {
  unsigned int u = __builtin_bit_cast(unsigned int, f);
  return u + 0x7fffu + ((u >> 16) & 1u);     // RNE bf16 in high 16 bits
}
__device__ __forceinline__ unsigned short f2bf(float f) {
  return (unsigned short)(rne16(f) >> 16);
}
__device__ __forceinline__ float bf2f(unsigned short h) {
  unsigned int u = ((unsigned int)h) << 16;
  return __builtin_bit_cast(float, u);
}
__device__ __forceinline__ f32x4 zero4() {
  f32x4 v; v.x = 0.f; v.y = 0.f; v.z = 0.f; v.w = 0.f; return v;
}
template <int CTRL>
__device__ __forceinline__ float dpp_add(float v) {
  int p = __builtin_amdgcn_update_dpp(0, __builtin_bit_cast(int, v),
                                      CTRL, 0xF, 0xF, true);
  return v + __builtin_bit_cast(float, p);
}
__device__ __forceinline__ float red16(float v) {  // sum over 16-lane group
  v = dpp_add<0xB1>(v);    // xor1
  v = dpp_add<0x4E>(v);    // xor2
  v = dpp_add<0x141>(v);   // row_half_mirror
  v = dpp_add<0x140>(v);   // row_mirror
  return v;
}

// ---------------------------------------------------------------------------
// Weight prep: fp32 row-major W[K][N] -> bf16 MFMA-fragment order:
//   frag f = kc*(N/16) + ntile (kc = 32-wide K slab); 64 lanes x 8 elems:
//   lane reads B[n = ntile*16 + (lane&15)][k = kc*32 + (lane>>4)*8 + e].
// ws regions (bf16 elems): stem @0 ; blocks @16384,81920,147456 ; head @212992 ;
// Z buffer @262144 (1024*128*128).
// ---------------------------------------------------------------------------
__global__ void prep_weights(const float* __restrict__ Win, const float* __restrict__ Wb,
                             const float* __restrict__ Wout, unsigned short* __restrict__ ws) {
  int g = blockIdx.x * 256 + threadIdx.x;
  if (g >= 30720) return;
  const float* W; int N; int local;
  if (g < 2048) { W = Win; N = 256; local = g; }
  else if (g < 26624) {
    int i = g - 2048; int blk = i >> 13; local = i & 8191;
    W = Wb + blk * 65536; N = 256;
  } else { W = Wout; N = 128; local = g - 26624; }
  int f = local >> 6, lane = local & 63;
  int NTL = N >> 4;
  int kc = f / NTL, ntile = f - kc * NTL;
  int n = ntile * 16 + (lane & 15);
  int k0 = kc * 32 + (lane >> 4) * 8;
  unsigned short o[8];
#pragma unroll
  for (int e = 0; e < 8; ++e) o[e] = f2bf(W[(size_t)(k0 + e) * N + n]);
  *reinterpret_cast<uint4*>(ws + (size_t)g * 8) = *reinterpret_cast<uint4*>(o);
}

// ---------------------------------------------------------------------------
// One GEMM layer over 64 rows, 8 waves (wave = column group wc), 4 M-tiles.
// Wave tile 64 x (16*NT); NT=2 for N=256, NT=1 for N=128.
// acc C-layout: row = 16*mt + 4*q + r, col = colbase + 16*nt + l16.
// MODE: 0 stem relu(ln) ; 1 residual (row-domain carry, 32/thread) ; 2 head ->
// direct global Z stores (no Xb store, no X2).
// Phase B: two passes h=0,1 over rows {32h + wave*4 + q}, streaming stats
// (pass reads Yb+bias 4-wide, red16, re-reads for normalize+pack).
// Xb/Yb ALIAS: X1 (K-loop reads done before Yb writes); X2 (Yb reads done
// before new-Xb stores; both passes' pk packed to regs first).
// ---------------------------------------------------------------------------
template <int KL, int N, int MODE>
__device__ __forceinline__ void layer(unsigned short* __restrict__ Xb,
                                      float* __restrict__ Yb, float* __restrict__ par,
                                      const unsigned short* __restrict__ Wf,
                                      int tid, int wave, int lane,
                                      const float* __restrict__ bias,
                                      const float* __restrict__ gam,
                                      const float* __restrict__ bet,
                                      float (&xprev)[32],
                                      unsigned short* __restrict__ Z, size_t rowglob) {
  constexpr int NT = N / 128;        // frags per wave per k-slab
  constexpr int NTL = N / 16;        // 16-col tiles across N
  constexpr int KC = KL / 32;        // 32-wide K slabs
  constexpr int J = N / 64;          // 4-col j-groups per thread (4 or 2)
  const int wc = wave;               // 8 waves = 8 column groups
  const int q = lane >> 4, l16 = lane & 15;
  const int colbase = wc * 16 * NT;
  const unsigned short* Wl = Wf + lane * 8;

  f32x4 acc[4][NT];
#pragma unroll
  for (int mt = 0; mt < 4; ++mt)
#pragma unroll
    for (int nt = 0; nt < NT; ++nt) acc[mt][nt] = zero4();

  bf16x8 bcur[NT];
#pragma unroll
  for (int nt = 0; nt < NT; ++nt)    // prefetch slab 0 before the barrier
    bcur[nt] = *reinterpret_cast<const bf16x8*>(Wl + (size_t)(wc * NT + nt) * 512);

  __syncthreads();                   // B1: prev phase-B Xb stores visible
  // stage params (bias|gamma|beta) -> LDS, read in phase B after B2
  for (int t = tid; t < 3 * N; t += 512) {
    float v = (t < N) ? bias[t] : (t < 2 * N) ? gam[t - N] : bet[t - 2 * N];
    par[t] = v;
  }
#pragma unroll
  for (int kc = 0; kc < KC; ++kc) {
    bf16x8 bnext[NT];
    if (kc + 1 < KC) {
#pragma unroll
      for (int nt = 0; nt < NT; ++nt)
        bnext[nt] = *reinterpret_cast<const bf16x8*>(
            Wl + (size_t)((kc + 1) * NTL + wc * NT + nt) * 512);
    }
    const int kk = kc * 32 + q * 8;
#pragma unroll
    for (int mt = 0; mt < 4; ++mt) {
      bf16x8 a = *reinterpret_cast<const bf16x8*>(Xb + (16 * mt + l16) * XB_STRIDE + kk);
#pragma unroll
      for (int nt = 0; nt < NT; ++nt)
        acc[mt][nt] = __builtin_amdgcn_mfma_f32_16x16x32_bf16(a, bcur[nt], acc[mt][nt], 0, 0, 0);
    }
    if (kc + 1 < KC) {
#pragma unroll
      for (int nt = 0; nt < NT; ++nt) bcur[nt] = bnext[nt];
    }
  }

  __syncthreads();                   // X1: all waves' Xb K-loop reads done

  // ---- phase A: raw acc -> Yb fp32 (bank residue 16q+4r+16nt+l16 : 2-way)
#pragma unroll
  for (int mt = 0; mt < 4; ++mt)
#pragma unroll
    for (int nt = 0; nt < NT; ++nt) {
      const int col = colbase + 16 * nt + l16;
#pragma unroll
      for (int r = 0; r < 4; ++r)
        Yb[(16 * mt + 4 * q + r) * YB_STRIDE + col] = acc[mt][nt][r];
    }
  __syncthreads();                   // B2: Yb + par complete

  // ---- phase B: two passes over rows {32h + wave*4 + q}, streaming stats
  const int cb = l16 * 4;
  unsigned int pk[2][2 * J];
#pragma unroll
  for (int h = 0; h < 2; ++h) {
    const int row = 32 * h + wave * 4 + q;
    float s1 = 0.f, s2 = 0.f;
#pragma unroll
    for (int j = 0; j < J; ++j) {
      f32x4 yv = *reinterpret_cast<const f32x4*>(Yb + row * YB_STRIDE + cb + 64 * j);
      f32x4 bv = *reinterpret_cast<const f32x4*>(par + cb + 64 * j);
#pragma unroll
      for (int i = 0; i < 4; ++i) {
        float t = yv[i] + bv[i];
        s1 += t; s2 = __builtin_fmaf(t, t, s2);
      }
    }
    s1 = red16(s1); s2 = red16(s2);
    const float mu = s1 * (1.0f / N);
    const float var = s2 * (1.0f / N) - mu * mu;
    const float rstd = rsqrtf(var + 1e-5f);
    const float nmr = -mu * rstd;
#pragma unroll
    for (int j = 0; j < J; ++j) {
      f32x4 yv = *reinterpret_cast<const f32x4*>(Yb + row * YB_STRIDE + cb + 64 * j);
      f32x4 bv = *reinterpret_cast<const f32x4*>(par + cb + 64 * j);
      f32x4 gv = *reinterpret_cast<const f32x4*>(par + N + cb + 64 * j);
      f32x4 ev = *reinterpret_cast<const f32x4*>(par + 2 * N + cb + 64 * j);
#pragma unroll
      for (int i = 0; i < 4; ++i) {
        const int e = 16 * h + 4 * j + i;
        float t = __builtin_fmaf(yv[i] + bv[i], rstd, nmr);
        float o = __builtin_fmaf(t, gv[i], ev[i]);
        float xv;
        if constexpr (MODE == 0) { xv = fmaxf(o, 0.f); xprev[e] = xv; }
        else if constexpr (MODE == 1) { xv = xprev[e] + fmaxf(o, 0.f); xprev[e] = xv; }
        else { xv = o; (void)e; }
        if (i & 1)
          pk[h][2 * j + (i >> 1)] = __builtin_amdgcn_perm(rne16(xv),
                         rne16(__builtin_bit_cast(float, pk[h][2 * j + (i >> 1)])), 0x07060302);
        else
          pk[h][2 * j + (i >> 1)] = __builtin_bit_cast(unsigned int, xv);
      }
    }
    if constexpr (MODE == 2) {       // head: direct global Z store per pass
#pragma unroll
      for (int j = 0; j < J; ++j)
        *reinterpret_cast<uint2*>(Z + (rowglob + row) * 128 + cb + 64 * j) =
            *reinterpret_cast<uint2*>(&pk[h][2 * j]);
    }
  }
  if constexpr (MODE != 2) {
    __syncthreads();                 // X2: all Yb reads done before Xb stores
    unsigned int* Xw = reinterpret_cast<unsigned int*>(Xb);
#pragma unroll
    for (int h = 0; h < 2; ++h) {
      const int row = 32 * h + wave * 4 + q;
#pragma unroll
      for (int j = 0; j < J; ++j)    // b64 store; bank residue 2(2q+l16): uniform
        *reinterpret_cast<uint2*>(Xw + row * 132 + 2 * l16 + 32 * j) =
            *reinterpret_cast<uint2*>(&pk[h][2 * j]);
    }
  }
}

// ---------------------------------------------------------------------------
// Kernel 1: ResNetMLP over 64 rows (half graph). 2048 blocks x 512 thr.
// waves_per_eu(4): 128 regs/wave at 4 waves/SIMD = 2 blocks/CU.
// ---------------------------------------------------------------------------
__global__ __attribute__((amdgpu_flat_work_group_size(512, 512), amdgpu_waves_per_eu(4)))
void mlp_main(const float* __restrict__ H, const unsigned short* __restrict__ ws,
              const float* __restrict__ b_in, const float* __restrict__ g_in,
              const float* __restrict__ beta_in,
              const float* __restrict__ bb, const float* __restrict__ gb,
              const float* __restrict__ betab,
              const float* __restrict__ b_out, const float* __restrict__ g_out,
              const float* __restrict__ beta_out,
              unsigned short* __restrict__ Z) {
  extern __shared__ char smem[];
  unsigned short* Xb = (unsigned short*)smem;          // ALIASED with Yb
  float* Yb = (float*)smem;                            // (see layer barriers)
  float* par = (float*)(smem + LDS_PAR);
  const int tid = threadIdx.x;
  const int wave = tid >> 6, lane = tid & 63;
  const size_t rowglob = (size_t)blockIdx.x * 64;

  // stage H (64 x 64 fp32) -> Xb bf16 ; 8 values/thread, packed uint4 store
  {
    int row = tid >> 3, c8 = (tid & 7) * 8;
    const float* hp = H + (rowglob + row) * 64 + c8;
    float4 f0 = *reinterpret_cast<const float4*>(hp);
    float4 f1 = *reinterpret_cast<const float4*>(hp + 4);
    uint4 o;
    o.x = __builtin_amdgcn_perm(rne16(f0.y), rne16(f0.x), 0x07060302);
    o.y = __builtin_amdgcn_perm(rne16(f0.w), rne16(f0.z), 0x07060302);
    o.z = __builtin_amdgcn_perm(rne16(f1.y), rne16(f1.x), 0x07060302);
    o.w = __builtin_amdgcn_perm(rne16(f1.w), rne16(f1.z), 0x07060302);
    *reinterpret_cast<uint4*>(Xb + row * XB_STRIDE + c8) = o;
  }

  float xprev[32];
  layer<64, 256, 0>(Xb, Yb, par, ws,           tid, wave, lane, b_in,     g_in,     beta_in,     xprev, Z, rowglob);
  layer<256, 256, 1>(Xb, Yb, par, ws + 16384,  tid, wave, lane, bb,       gb,       betab,       xprev, Z, rowglob);
  layer<256, 256, 1>(Xb, Yb, par, ws + 81920,  tid, wave, lane, bb + 256, gb + 256, betab + 256, xprev, Z, rowglob);
  layer<256, 256, 1>(Xb, Yb, par, ws + 147456, tid, wave, lane, bb + 512, gb + 512, betab + 512, xprev, Z, rowglob);
  layer<256, 128, 2>(Xb, Yb, par, ws + 212992, tid, wave, lane, b_out,    g_out,    beta_out,    xprev, Z, rowglob);
}

// ---------------------------------------------------------------------------
// Kernel 2: per-graph gram + mean-distance + softmax + weighted pool.
// 1024 blocks x 512 thr; Z[g] (128x128 bf16) staged to LDS. (R7-verified.)
// ---------------------------------------------------------------------------
__global__ __attribute__((amdgpu_flat_work_group_size(512, 512)))
void pool_main(const unsigned short* __restrict__ Z, float* __restrict__ out) {
  __shared__ unsigned short Zb[128 * ZB_STRIDE];
  __shared__ float sqv[128], sm[128], smw[128];
  const int tid = threadIdx.x;
  const int g = blockIdx.x;
  const int wave = tid >> 6, lane = tid & 63;
  const int q = lane >> 4, l16 = lane & 15;

  {
    int zr = tid >> 2, zc = (tid & 3) * 32;
    const uint4* zp = reinterpret_cast<const uint4*>(Z + ((size_t)g * 128 + zr) * 128 + zc);
    uint4* zd = reinterpret_cast<uint4*>(Zb + zr * ZB_STRIDE + zc);
    zd[0] = zp[0]; zd[1] = zp[1]; zd[2] = zp[2]; zd[3] = zp[3];
  }
  __syncthreads();

  // gram G = Z Z^T : wave owns 16 rows x 128 cols
  f32x4 g2[8];
#pragma unroll
  for (int nt = 0; nt < 8; ++nt) g2[nt] = zero4();
#pragma unroll
  for (int ks = 0; ks < 4; ++ks) {
    int kk = ks * 32 + q * 8;
    bf16x8 a = *reinterpret_cast<const bf16x8*>(Zb + (16 * wave + l16) * ZB_STRIDE + kk);
#pragma unroll
    for (int nt = 0; nt < 8; ++nt) {
      bf16x8 bfr = *reinterpret_cast<const bf16x8*>(Zb + (16 * nt + l16) * ZB_STRIDE + kk);
      g2[nt] = __builtin_amdgcn_mfma_f32_16x16x32_bf16(a, bfr, g2[nt], 0, 0, 0);
    }
  }
  // publish sq_i = G_ii (diag) so d_ii == sqrt(1e-12) exactly like ref
  if ((l16 >> 2) == q) {
#pragma unroll
    for (int nt = 0; nt < 8; ++nt)
      if (nt == wave) {
#pragma unroll
        for (int r = 0; r < 4; ++r)
          if ((l16 & 3) == r) sqv[16 * wave + l16] = g2[nt][r];
      }
  }
  __syncthreads();
  // distances and s_i = mean_j d_ij
  float sqi[4];
#pragma unroll
  for (int r = 0; r < 4; ++r) sqi[r] = sqv[16 * wave + q * 4 + r];
  float sp[4] = {0.f, 0.f, 0.f, 0.f};
#pragma unroll
  for (int nt = 0; nt < 8; ++nt) {
    float sqj = sqv[16 * nt + l16];
#pragma unroll
    for (int r = 0; r < 4; ++r) {
      float d2 = sqi[r] + sqj - 2.0f * g2[nt][r];
      sp[r] += sqrtf(fmaxf(d2, 0.f) + 1e-12f);
    }
  }
#pragma unroll
  for (int d = 1; d < 16; d <<= 1) {
#pragma unroll
    for (int r = 0; r < 4; ++r) { float t = sp[r]; t += __shfl_xor(t, d); sp[r] = t; }
  }
  if (l16 == 0) {
#pragma unroll
    for (int r = 0; r < 4; ++r) sm[16 * wave + q * 4 + r] = sp[r] * (1.0f / 128.0f);
  }
  __syncthreads();
  // softmax(s/TAU) by wave 0 (1/TAU = 4)
  if (wave == 0) {
    float l0 = sm[lane] * 4.0f;
    float l1 = sm[lane + 64] * 4.0f;
    float mx = fmaxf(l0, l1);
#pragma unroll
    for (int d = 1; d < 64; d <<= 1) mx = fmaxf(mx, __shfl_xor(mx, d));
    float e0 = __expf(l0 - mx), e1 = __expf(l1 - mx);
    float ss = e0 + e1;
#pragma unroll
    for (int d = 1; d < 64; d <<= 1) ss += __shfl_xor(ss, d);
    float inv = 1.0f / ss;
    float w0 = e0 * inv, w1 = e1 * inv;
    smw[lane] = w0;
    smw[lane + 64] = w1;
    out[131072 + g * 128 + lane] = w0;
    out[131072 + g * 128 + 64 + lane] = w1;
  }
  __syncthreads();
  // v_loc = sum_i w_i * Z[i,:]
  {
    int c = 16 * wave + l16;
    float acv = 0.f;
#pragma unroll
    for (int i0 = 0; i0 < 32; ++i0) {
      int i = q * 32 + i0;
      acv += smw[i] * bf2f(Zb[i * ZB_STRIDE + c]);
    }
    acv += __shfl_xor(acv, 16);
    acv += __shfl_xor(acv, 32);
    if (q == 0) out[g * 128 + c] = acv;
  }
}

// ---------------------------------------------------------------------------
extern "C" void kernel_launch(void* const* d_in, const int* in_sizes, int n_in,
                              void* d_out, int out_size, void* d_ws, size_t ws_size,
                              hipStream_t stream) {
  (void)in_sizes; (void)n_in; (void)out_size; (void)ws_size;
  const float* H        = (const float*)d_in[0];
  // d_in[1] = batch_ptr (uniform 128/graph, unused)
  const float* W_in     = (const float*)d_in[2];
  const float* b_in     = (const float*)d_in[3];
  const float* g_in     = (const float*)d_in[4];
  const float* beta_in  = (const float*)d_in[5];
  const float* Wb       = (const float*)d_in[6];
  const float* bb       = (const float*)d_in[7];
  const float* gb       = (const float*)d_in[8];
  const float* betab    = (const float*)d_in[9];
  const float* W_out    = (const float*)d_in[10];
  const float* b_out    = (const float*)d_in[11];
  const float* g_out    = (const float*)d_in[12];
  const float* beta_out = (const float*)d_in[13];
  float* out = (float*)d_out;
  unsigned short* ws = (unsigned short*)d_ws;
  unsigned short* Z = ws + 262144;      // 1024*128*128 bf16 = 33.5 MB

  prep_weights<<<120, 256, 0, stream>>>(W_in, Wb, W_out, ws);
  hipFuncSetAttribute(reinterpret_cast<const void*>(mlp_main),
                      hipFuncAttributeMaxDynamicSharedMemorySize, LDS_TOTAL);
  mlp_main<<<2048, 512, LDS_TOTAL, stream>>>(H, ws, b_in, g_in, beta_in,
                                             bb, gb, betab, b_out, g_out, beta_out, Z);
  pool_main<<<1024, 512, 0, stream>>>(Z, out);
}